// Round 3
// baseline (1236.931 us; speedup 1.0000x reference)
//
#include <hip/hip_runtime.h>

#define BB 128
#define LL 336
#define CC 862
#define PRED 96
#define WIN 12
#define S_IN 28
#define S_OUT 8
#define NQ 7                      // s chunks of 4
#define CT 32
#define NTILES ((CC + CT - 1) / CT)   // 27

#define SQRT12F 3.4641016151377544f

// -Sb(t)/sqrt(12), Sb(t) = 2*sum_{k=1..5} sin(pi*k*t/6)   (exact closed forms)
__device__ const float COEFP[12] = {
    0.0f, -2.1547005383792515f, 0.0f, -0.5773502691896258f,
    0.0f, -0.15470053837925146f, 0.0f, 0.15470053837925146f,
    0.0f,  0.5773502691896258f, 0.0f,  2.1547005383792515f
};

// ---- prep kernels ----

// repacked layout: wX4[((q*S_OUT + p)*CC + c)*4 + j]  = wX[c][p][4q+j]
__global__ void prep_w4(const float* __restrict__ wA, const float* __restrict__ wP,
                        float* __restrict__ wA4, float* __restrict__ wP4) {
    int i = blockIdx.x * 256 + threadIdx.x;
    if (i >= NQ * S_OUT * CC * 4) return;
    int j  = i & 3;
    int c  = (i >> 2) % CC;
    int p  = (i / (4 * CC)) % S_OUT;
    int q  = i / (4 * CC * S_OUT);
    int s  = 4 * q + j;
    int src = (c * S_OUT + p) * S_IN + s;
    wA4[i] = wA[src];
    wP4[i] = wP[src];
}

__global__ void prep_mcoef(const float* __restrict__ wA, float* __restrict__ mcoefT) {
    int i = blockIdx.x * 256 + threadIdx.x;          // [p][c]
    if (i >= S_OUT * CC) return;
    int c = i % CC;
    int p = i / CC;
    float s = 0.f;
    for (int k = 0; k < S_IN; ++k) s += wA[(c * S_OUT + p) * S_IN + k];
    mcoefT[i] = 1.0f - s;
}

__global__ void prep_bias(const float* __restrict__ bA, const float* __restrict__ bP,
                          float* __restrict__ biasv) {
    int i = blockIdx.x * 256 + threadIdx.x;          // [t][p][c]
    if (i >= 12 * S_OUT * CC) return;
    int c = i % CC;
    int tp = i / CC;
    int p = tp % S_OUT;
    int t = tp / S_OUT;
    float v = COEFP[t] * bP[c * S_OUT + p];
    if (t == 0) v += SQRT12F * bA[c * S_OUT + p];
    biasv[i] = v;
}

// ---- fused main kernel, streaming s-chunks, A/P accumulators ----
// thread = (cc 0..31, pair 0..7); pairs 0..6 active; t=pair, tr=(12-t)%12

template <bool TRANS>
__global__ __launch_bounds__(256, 8) void fused3(
    const float* __restrict__ x,
    const float* __restrict__ wA4, const float* __restrict__ wP4,
    const float* __restrict__ mcoefT, const float* __restrict__ biasv,
    const float* __restrict__ wA_raw, const float* __restrict__ wP_raw,
    const float* __restrict__ bAr, const float* __restrict__ bPr,
    float* __restrict__ out)
{
    __shared__ float ssum[7][CT];    // 896 B

    const int b    = blockIdx.y;
    const int c0   = blockIdx.x * CT;
    const int NC   = min(CT, CC - c0);
    const int tid  = threadIdx.x;
    const int cc   = tid & 31;
    const int pair = tid >> 5;          // 0..7
    const int c    = c0 + cc;
    const int cl   = (c < CC) ? c : (CC - 1);   // clamped for loads
    const int t    = (pair < 7) ? pair : 0;
    const int tr   = (12 - t) % 12;
    const bool active = (pair < 7) && (cc < NC);

    float A[S_OUT], P[S_OUT];
    #pragma unroll
    for (int p = 0; p < S_OUT; ++p) { A[p] = 0.f; P[p] = 0.f; }
    float su = 0.f;
    float swsum = 0.f;                  // fallback: sum of wA over s (per p folded later)

    const float* xb = x + ((size_t)b * LL) * CC + cl;

    #pragma unroll
    for (int q = 0; q < NQ; ++q) {
        float u4[4], v4[4];
        #pragma unroll
        for (int j = 0; j < 4; ++j) {
            const int s = 4 * q + j;
            float xt = xb[(size_t)(s * WIN + t)  * CC];
            float xr = xb[(size_t)(s * WIN + tr) * CC];
            u4[j] = xt + xr;
            v4[j] = xt - xr;
        }
        su += (u4[0] + u4[1]) + (u4[2] + u4[3]);

        if (TRANS) {
            const float4* wa4 = reinterpret_cast<const float4*>(wA4) + (size_t)(q * S_OUT) * CC + cl;
            const float4* wp4 = reinterpret_cast<const float4*>(wP4) + (size_t)(q * S_OUT) * CC + cl;
            #pragma unroll
            for (int p = 0; p < S_OUT; ++p) {
                float4 wa = wa4[(size_t)p * CC];
                float4 wp = wp4[(size_t)p * CC];
                A[p] = fmaf(wa.x, u4[0], A[p]);
                A[p] = fmaf(wa.y, u4[1], A[p]);
                A[p] = fmaf(wa.z, u4[2], A[p]);
                A[p] = fmaf(wa.w, u4[3], A[p]);
                P[p] = fmaf(wp.x, v4[0], P[p]);
                P[p] = fmaf(wp.y, v4[1], P[p]);
                P[p] = fmaf(wp.z, v4[2], P[p]);
                P[p] = fmaf(wp.w, v4[3], P[p]);
            }
        } else {
            #pragma unroll
            for (int p = 0; p < S_OUT; ++p) {
                const float* wa = wA_raw + (size_t)(cl * S_OUT + p) * S_IN + 4 * q;
                const float* wp = wP_raw + (size_t)(cl * S_OUT + p) * S_IN + 4 * q;
                #pragma unroll
                for (int j = 0; j < 4; ++j) {
                    A[p] = fmaf(wa[j], u4[j], A[p]);
                    P[p] = fmaf(wp[j], v4[j], P[p]);
                }
            }
        }
    }

    // per-channel mean from pair u-sums
    if (pair < 7) {
        ssum[pair][cc] = (t == 0 || t == 6) ? 0.5f * su : su;
    }
    __syncthreads();
    float mean = 0.f;
    #pragma unroll
    for (int r = 0; r < 7; ++r) mean += ssum[r][cc];
    mean *= (1.0f / LL);

    if (!active) return;

    float* ob = out + ((size_t)b * PRED) * CC + c;

    #pragma unroll
    for (int p = 0; p < S_OUT; ++p) {
        float mc, bias_t, bias_r;
        if (TRANS) {
            mc     = mcoefT[p * CC + c];
            bias_t = biasv[(t  * S_OUT + p) * CC + c];
            bias_r = biasv[(tr * S_OUT + p) * CC + c];
        } else {
            float sw = 0.f;
            const float* wa = wA_raw + (size_t)(c * S_OUT + p) * S_IN;
            #pragma unroll
            for (int s = 0; s < S_IN; ++s) sw += wa[s];
            mc = 1.0f - sw;
            float ba = bAr[c * S_OUT + p], bp = bPr[c * S_OUT + p];
            bias_t = COEFP[t]  * bp + (t == 0 ? SQRT12F * ba : 0.f);
            bias_r = COEFP[tr] * bp;
        }
        const float mb = mean * mc;
        ob[(size_t)(p * WIN + t) * CC] = 0.5f * (A[p] + P[p]) + mb + bias_t;
        if (t != tr) {
            ob[(size_t)(p * WIN + tr) * CC] = 0.5f * (A[p] - P[p]) + mb + bias_r;
        }
    }
    (void)swsum;
}

extern "C" void kernel_launch(void* const* d_in, const int* in_sizes, int n_in,
                              void* d_out, int out_size, void* d_ws, size_t ws_size,
                              hipStream_t stream) {
    const float* x  = (const float*)d_in[0];
    const float* wA = (const float*)d_in[1];
    const float* bA = (const float*)d_in[2];
    const float* wP = (const float*)d_in[3];
    const float* bP = (const float*)d_in[4];
    float* out = (float*)d_out;

    const size_t nW  = (size_t)NQ * S_OUT * CC * 4;  // 193088
    const size_t nM  = (size_t)S_OUT * CC;           // 6896
    const size_t nBv = (size_t)12 * S_OUT * CC;      // 82752
    const size_t need = (2 * nW + nM + nBv) * sizeof(float);

    dim3 grid(NTILES, BB);

    if (ws_size >= need) {
        float* wA4    = (float*)d_ws;
        float* wP4    = wA4 + nW;
        float* mcoefT = wP4 + nW;
        float* biasv  = mcoefT + nM;

        prep_w4<<<(int)((nW + 255) / 256), 256, 0, stream>>>(wA, wP, wA4, wP4);
        prep_mcoef<<<(int)((nM + 255) / 256), 256, 0, stream>>>(wA, mcoefT);
        prep_bias<<<(int)((nBv + 255) / 256), 256, 0, stream>>>(bA, bP, biasv);

        fused3<true><<<grid, 256, 0, stream>>>(
            x, wA4, wP4, mcoefT, biasv,
            nullptr, nullptr, nullptr, nullptr, out);
    } else {
        fused3<false><<<grid, 256, 0, stream>>>(
            x, nullptr, nullptr, nullptr, nullptr,
            wA, wP, bA, bP, out);
    }
}

// Round 4
// 86.440 us; speedup vs baseline: 14.3096x; 14.3096x over previous
//
#include <hip/hip_runtime.h>

#define BB 128
#define LL 336
#define CC 862
#define PRED 96
#define WIN 12
#define S_IN 28
#define S_OUT 8
#define NQ 7                      // s chunks of 4
#define CT 32
#define NTILES ((CC + CT - 1) / CT)   // 27

#define SQRT12F 3.4641016151377544f

// -Sb(t)/sqrt(12), Sb(t) = 2*sum_{k=1..5} sin(pi*k*t/6)   (exact closed forms)
__device__ const float COEFP[12] = {
    0.0f, -2.1547005383792515f, 0.0f, -0.5773502691896258f,
    0.0f, -0.15470053837925146f, 0.0f, 0.15470053837925146f,
    0.0f,  0.5773502691896258f, 0.0f,  2.1547005383792515f
};

// ---- prep kernels ----

// repacked layout: wX4[((q*S_OUT + p)*CC + c)*4 + j]  = wX[c][p][4q+j]
__global__ void prep_w4(const float* __restrict__ wA, const float* __restrict__ wP,
                        float* __restrict__ wA4, float* __restrict__ wP4) {
    int i = blockIdx.x * 256 + threadIdx.x;
    if (i >= NQ * S_OUT * CC * 4) return;
    int j  = i & 3;
    int c  = (i >> 2) % CC;
    int p  = (i / (4 * CC)) % S_OUT;
    int q  = i / (4 * CC * S_OUT);
    int s  = 4 * q + j;
    int src = (c * S_OUT + p) * S_IN + s;
    wA4[i] = wA[src];
    wP4[i] = wP[src];
}

__global__ void prep_mcoef(const float* __restrict__ wA, float* __restrict__ mcoefT) {
    int i = blockIdx.x * 256 + threadIdx.x;          // [p][c]
    if (i >= S_OUT * CC) return;
    int c = i % CC;
    int p = i / CC;
    float s = 0.f;
    for (int k = 0; k < S_IN; ++k) s += wA[(c * S_OUT + p) * S_IN + k];
    mcoefT[i] = 1.0f - s;
}

__global__ void prep_bias(const float* __restrict__ bA, const float* __restrict__ bP,
                          float* __restrict__ biasv) {
    int i = blockIdx.x * 256 + threadIdx.x;          // [t][p][c]
    if (i >= 12 * S_OUT * CC) return;
    int c = i % CC;
    int tp = i / CC;
    int p = tp % S_OUT;
    int t = tp / S_OUT;
    float v = COEFP[t] * bP[c * S_OUT + p];
    if (t == 0) v += SQRT12F * bA[c * S_OUT + p];
    biasv[i] = v;
}

// ---- fused main kernel, streaming s-chunks, A/P accumulators ----
// thread = (cc 0..31, pair 0..7); pairs 0..6 active; t=pair, tr=(12-t)%12
// launch_bounds(256,4): VGPR cap 128 — rolled q-loop needs ~90, NO spill.
// (256,8) in round 3 forced <=64 and spilled the accumulators: 2.6 GB scratch writes.

template <bool TRANS>
__global__ __launch_bounds__(256, 4) void fused4(
    const float* __restrict__ x,
    const float* __restrict__ wA4, const float* __restrict__ wP4,
    const float* __restrict__ mcoefT, const float* __restrict__ biasv,
    const float* __restrict__ wA_raw, const float* __restrict__ wP_raw,
    const float* __restrict__ bAr, const float* __restrict__ bPr,
    float* __restrict__ out)
{
    __shared__ float ssum[7][CT];    // 896 B

    const int b    = blockIdx.y;
    const int c0   = blockIdx.x * CT;
    const int NC   = min(CT, CC - c0);
    const int tid  = threadIdx.x;
    const int cc   = tid & 31;
    const int pair = tid >> 5;          // 0..7
    const int c    = c0 + cc;
    const int cl   = (c < CC) ? c : (CC - 1);   // clamped for loads
    const int t    = (pair < 7) ? pair : 0;
    const int tr   = (12 - t) % 12;
    const bool active = (pair < 7) && (cc < NC);

    float A[S_OUT], P[S_OUT];
    #pragma unroll
    for (int p = 0; p < S_OUT; ++p) { A[p] = 0.f; P[p] = 0.f; }
    float su = 0.f;

    const float* xb = x + ((size_t)b * LL) * CC + cl;

    #pragma unroll 1
    for (int q = 0; q < NQ; ++q) {
        float u4[4], v4[4];
        #pragma unroll
        for (int j = 0; j < 4; ++j) {
            const int s = 4 * q + j;
            float xt = xb[(size_t)(s * WIN + t)  * CC];
            float xr = xb[(size_t)(s * WIN + tr) * CC];
            u4[j] = xt + xr;
            v4[j] = xt - xr;
        }
        su += (u4[0] + u4[1]) + (u4[2] + u4[3]);

        if (TRANS) {
            const float4* wa4 = reinterpret_cast<const float4*>(wA4) + (size_t)(q * S_OUT) * CC + cl;
            const float4* wp4 = reinterpret_cast<const float4*>(wP4) + (size_t)(q * S_OUT) * CC + cl;
            #pragma unroll
            for (int p = 0; p < S_OUT; ++p) {
                float4 wa = wa4[(size_t)p * CC];
                float4 wp = wp4[(size_t)p * CC];
                A[p] = fmaf(wa.x, u4[0], A[p]);
                A[p] = fmaf(wa.y, u4[1], A[p]);
                A[p] = fmaf(wa.z, u4[2], A[p]);
                A[p] = fmaf(wa.w, u4[3], A[p]);
                P[p] = fmaf(wp.x, v4[0], P[p]);
                P[p] = fmaf(wp.y, v4[1], P[p]);
                P[p] = fmaf(wp.z, v4[2], P[p]);
                P[p] = fmaf(wp.w, v4[3], P[p]);
            }
        } else {
            #pragma unroll
            for (int p = 0; p < S_OUT; ++p) {
                const float* wa = wA_raw + (size_t)(cl * S_OUT + p) * S_IN + 4 * q;
                const float* wp = wP_raw + (size_t)(cl * S_OUT + p) * S_IN + 4 * q;
                #pragma unroll
                for (int j = 0; j < 4; ++j) {
                    A[p] = fmaf(wa[j], u4[j], A[p]);
                    P[p] = fmaf(wp[j], v4[j], P[p]);
                }
            }
        }
    }

    // per-channel mean from pair u-sums
    if (pair < 7) {
        ssum[pair][cc] = (t == 0 || t == 6) ? 0.5f * su : su;
    }
    __syncthreads();
    float mean = 0.f;
    #pragma unroll
    for (int r = 0; r < 7; ++r) mean += ssum[r][cc];
    mean *= (1.0f / LL);

    if (!active) return;

    float* ob = out + ((size_t)b * PRED) * CC + c;

    #pragma unroll
    for (int p = 0; p < S_OUT; ++p) {
        float mc, bias_t, bias_r;
        if (TRANS) {
            mc     = mcoefT[p * CC + c];
            bias_t = biasv[(t  * S_OUT + p) * CC + c];
            bias_r = biasv[(tr * S_OUT + p) * CC + c];
        } else {
            float sw = 0.f;
            const float* wa = wA_raw + (size_t)(c * S_OUT + p) * S_IN;
            #pragma unroll
            for (int s = 0; s < S_IN; ++s) sw += wa[s];
            mc = 1.0f - sw;
            float ba = bAr[c * S_OUT + p], bp = bPr[c * S_OUT + p];
            bias_t = COEFP[t]  * bp + (t == 0 ? SQRT12F * ba : 0.f);
            bias_r = COEFP[tr] * bp;
        }
        const float mb = mean * mc;
        ob[(size_t)(p * WIN + t) * CC] = 0.5f * (A[p] + P[p]) + mb + bias_t;
        if (t != tr) {
            ob[(size_t)(p * WIN + tr) * CC] = 0.5f * (A[p] - P[p]) + mb + bias_r;
        }
    }
}

extern "C" void kernel_launch(void* const* d_in, const int* in_sizes, int n_in,
                              void* d_out, int out_size, void* d_ws, size_t ws_size,
                              hipStream_t stream) {
    const float* x  = (const float*)d_in[0];
    const float* wA = (const float*)d_in[1];
    const float* bA = (const float*)d_in[2];
    const float* wP = (const float*)d_in[3];
    const float* bP = (const float*)d_in[4];
    float* out = (float*)d_out;

    const size_t nW  = (size_t)NQ * S_OUT * CC * 4;  // 193088
    const size_t nM  = (size_t)S_OUT * CC;           // 6896
    const size_t nBv = (size_t)12 * S_OUT * CC;      // 82752
    const size_t need = (2 * nW + nM + nBv) * sizeof(float);

    dim3 grid(NTILES, BB);

    if (ws_size >= need) {
        float* wA4    = (float*)d_ws;
        float* wP4    = wA4 + nW;
        float* mcoefT = wP4 + nW;
        float* biasv  = mcoefT + nM;

        prep_w4<<<(int)((nW + 255) / 256), 256, 0, stream>>>(wA, wP, wA4, wP4);
        prep_mcoef<<<(int)((nM + 255) / 256), 256, 0, stream>>>(wA, mcoefT);
        prep_bias<<<(int)((nBv + 255) / 256), 256, 0, stream>>>(bA, bP, biasv);

        fused4<true><<<grid, 256, 0, stream>>>(
            x, wA4, wP4, mcoefT, biasv,
            nullptr, nullptr, nullptr, nullptr, out);
    } else {
        fused4<false><<<grid, 256, 0, stream>>>(
            x, nullptr, nullptr, nullptr, nullptr,
            wA, wP, bA, bP, out);
    }
}